// Round 1
// baseline (487.740 us; speedup 1.0000x reference)
//
#include <hip/hip_runtime.h>
#include <hip/hip_bf16.h>
#include <math.h>

// Problem constants
#define D_MODEL 2048
#define HD      128
#define NB      4
#define TT      4096
#define M_TOT   (NB * TT)   // 16384

typedef __attribute__((ext_vector_type(8))) short bf16x8;   // 8 bf16 = 4 VGPRs (guide-verified typedef)
typedef __attribute__((ext_vector_type(4))) float f32x4;

__device__ __forceinline__ ushort f2bf(float f) {
    union { float f; unsigned int u; } v; v.f = f;
    unsigned int u = v.u;
    unsigned int r = (u + 0x7FFFu + ((u >> 16) & 1u)) >> 16;   // RNE
    return (ushort)r;
}

// ---------------------------------------------------------------------------
// Kernel 1: x fp32 -> bf16 (one-time, so projection K-loop has no cvt)
// ---------------------------------------------------------------------------
__global__ void cvt_x_kernel(const float* __restrict__ x, ushort* __restrict__ xb) {
    const int N4 = M_TOT * D_MODEL / 4;
    for (int i = blockIdx.x * blockDim.x + threadIdx.x; i < N4; i += gridDim.x * blockDim.x) {
        float4 f = ((const float4*)x)[i];
        ushort4 o;
        o.x = f2bf(f.x); o.y = f2bf(f.y); o.z = f2bf(f.z); o.w = f2bf(f.w);
        ((ushort4*)xb)[i] = o;
    }
}

// ---------------------------------------------------------------------------
// Kernel 2: WT[p][n][k] = bf16(W_p[k][n])  (transpose so B-frags are k-contiguous)
// ---------------------------------------------------------------------------
__global__ void wt_kernel(const float* __restrict__ Wq, const float* __restrict__ Wk,
                          const float* __restrict__ Wv, ushort* __restrict__ WT) {
    int p = blockIdx.y;
    const float* W = (p == 0) ? Wq : ((p == 1) ? Wk : Wv);
    int e = blockIdx.x * 256 + threadIdx.x;     // e over 128*2048
    int n = e & 127;                            // coalesced reads (n fastest)
    int k = e >> 7;
    WT[(size_t)p * (128 * 2048) + (size_t)n * 2048 + k] = f2bf(W[(size_t)k * 128 + n]);
}

// ---------------------------------------------------------------------------
// Kernel 3: QKV projection. Block = 128 rows x 128 cols, 4 waves.
// Wave w: rows [32w,32w+32) as 2 m-tiles; 8 n-tiles of 16.
// A (x) staged bf16 in LDS; B (WT) read directly from global (L2-resident).
// p==2 (V) writes transposed: Vt[b][h][t] so attention PV B-frags are s-contiguous.
// ---------------------------------------------------------------------------
__global__ __launch_bounds__(256) void proj_kernel(
        const ushort* __restrict__ xb, const ushort* __restrict__ WT,
        const float* __restrict__ bq, const float* __restrict__ bk, const float* __restrict__ bv,
        ushort* __restrict__ Qb, ushort* __restrict__ Kb, ushort* __restrict__ Vt) {
    const int p  = blockIdx.y;
    const int m0 = blockIdx.x * 128;
    const ushort* Wp   = WT + (size_t)p * (128 * 2048);
    const float*  bias = (p == 0) ? bq : ((p == 1) ? bk : bv);

    __shared__ ushort xs[128 * 32];   // [m][k] bf16, 64B rows (conflict-free for A-frags)

    const int tid  = threadIdx.x;
    const int lane = tid & 63;
    const int wv   = tid >> 6;
    const int quad = lane >> 4;
    const int ln16 = lane & 15;

    f32x4 acc[2][8];
    for (int mt = 0; mt < 2; mt++)
        for (int nt = 0; nt < 8; nt++)
            acc[mt][nt] = (f32x4){0.f, 0.f, 0.f, 0.f};

    for (int k0 = 0; k0 < D_MODEL; k0 += 32) {
        __syncthreads();   // xs reuse from previous iter
        // stage x tile [128][32] bf16: 512 chunks of 16B, 2 per thread
        for (int i = 0; i < 2; i++) {
            int c  = i * 256 + tid;
            int m  = c >> 2;
            int kc = c & 3;
            uint4 v = *(const uint4*)(xb + (size_t)(m0 + m) * D_MODEL + k0 + kc * 8);
            *(uint4*)&xs[c * 8] = v;
        }
        __syncthreads();

        bf16x8 a[2];
        a[0] = *(const bf16x8*)&xs[(32 * wv + ln16) * 32 + quad * 8];
        a[1] = *(const bf16x8*)&xs[(32 * wv + 16 + ln16) * 32 + quad * 8];
        for (int nt = 0; nt < 8; nt++) {
            bf16x8 b = *(const bf16x8*)(Wp + (size_t)(nt * 16 + ln16) * 2048 + k0 + quad * 8);
            acc[0][nt] = __builtin_amdgcn_mfma_f32_16x16x32_bf16(a[0], b, acc[0][nt], 0, 0, 0);
            acc[1][nt] = __builtin_amdgcn_mfma_f32_16x16x32_bf16(a[1], b, acc[1][nt], 0, 0, 0);
        }
    }

    // Epilogue: + bias, write bf16. C/D layout: col=lane&15, row=quad*4+reg.
    for (int nt = 0; nt < 8; nt++) {
        int   col = nt * 16 + ln16;
        float bc  = bias[col];
        for (int mt = 0; mt < 2; mt++) {
            int rbase = m0 + 32 * wv + 16 * mt + quad * 4;
            if (p < 2) {
                ushort* O = (p == 0) ? Qb : Kb;
                for (int r = 0; r < 4; r++)
                    O[(size_t)(rbase + r) * HD + col] = f2bf(acc[mt][nt][r] + bc);
            } else {
                // transposed V: Vt[b][h][t], 4 consecutive t -> one 8B store
                int b = rbase >> 12;          // /4096
                int t = rbase & 4095;
                ushort4 o;
                o.x = f2bf(acc[mt][nt][0] + bc);
                o.y = f2bf(acc[mt][nt][1] + bc);
                o.z = f2bf(acc[mt][nt][2] + bc);
                o.w = f2bf(acc[mt][nt][3] + bc);
                *(ushort4*)(Vt + ((size_t)b * HD + col) * TT + t) = o;
            }
        }
    }
}

// ---------------------------------------------------------------------------
// Kernel 4: flash attention, causal. Block = 64 q-rows (BQ=64), 4 waves,
// wave w owns q-rows [16w,16w+16) -> softmax state is wave-private.
// S-tiles of 64 keys. LDS rows padded to odd multiples of 16B => all frag
// reads spread evenly over the 8 bank chunk-positions (conflict-free).
// ---------------------------------------------------------------------------
#define SCALE 0.08838834764831845f   // 1/sqrt(128)

__global__ __launch_bounds__(256) void attn_kernel(
        const ushort* __restrict__ Qb, const ushort* __restrict__ Kb,
        const ushort* __restrict__ Vt, float* __restrict__ out) {
    const int bb = blockIdx.y;
    const int qt = blockIdx.x;
    const int q0 = qt * 64;

    __shared__ ushort Qs[64 * 136];   // [q][h], stride 136 ushorts = 272B = 17*16B
    __shared__ ushort Ks[64 * 136];   // [s][h]
    __shared__ ushort Vs[128 * 72];   // [h][s], stride 144B = 9*16B
    __shared__ ushort Ps[64 * 72];    // [q][s]

    const int tid  = threadIdx.x;
    const int lane = tid & 63;
    const int wv   = tid >> 6;
    const int quad = lane >> 4;
    const int ln16 = lane & 15;

    // stage Q tile once: 1024 chunks of 16B
    for (int i = 0; i < 4; i++) {
        int c = i * 256 + tid;
        int row = c >> 4, kc = c & 15;
        uint4 v = *(const uint4*)(Qb + ((size_t)(bb * TT + q0 + row)) * HD + kc * 8);
        *(uint4*)&Qs[row * 136 + kc * 8] = v;
    }

    f32x4 o_acc[8];
    for (int nt = 0; nt < 8; nt++) o_acc[nt] = (f32x4){0.f, 0.f, 0.f, 0.f};
    float m_i[4], l_i[4];
    for (int r = 0; r < 4; r++) { m_i[r] = -INFINITY; l_i[r] = 0.f; }

    const int nst = qt + 1;
    for (int st = 0; st < nst; st++) {
        const int s0 = st * 64;
        __syncthreads();   // Ks/Vs/Ps reuse from previous iter (also covers Q staging on st==0)
        // stage K tile [64][128]
        for (int i = 0; i < 4; i++) {
            int c = i * 256 + tid;
            int row = c >> 4, kc = c & 15;
            uint4 v = *(const uint4*)(Kb + ((size_t)(bb * TT + s0 + row)) * HD + kc * 8);
            *(uint4*)&Ks[row * 136 + kc * 8] = v;
        }
        // stage V^T tile [128][64]
        for (int i = 0; i < 4; i++) {
            int c = i * 256 + tid;
            int h = c >> 3, sc = c & 7;
            uint4 v = *(const uint4*)(Vt + ((size_t)bb * HD + h) * TT + s0 + sc * 8);
            *(uint4*)&Vs[h * 72 + sc * 8] = v;
        }
        __syncthreads();

        // ---- S = Q K^T (wave: 16 q-rows x 64 s-cols = 4 n-tiles) ----
        f32x4 sacc[4];
        for (int nt = 0; nt < 4; nt++) sacc[nt] = (f32x4){0.f, 0.f, 0.f, 0.f};
        for (int kc = 0; kc < 4; kc++) {
            bf16x8 a = *(const bf16x8*)&Qs[(16 * wv + ln16) * 136 + kc * 32 + quad * 8];
            for (int nt = 0; nt < 4; nt++) {
                bf16x8 b = *(const bf16x8*)&Ks[(nt * 16 + ln16) * 136 + kc * 32 + quad * 8];
                sacc[nt] = __builtin_amdgcn_mfma_f32_16x16x32_bf16(a, b, sacc[nt], 0, 0, 0);
            }
        }

        // ---- scale + causal mask + online softmax (rows wave-private) ----
        const bool diag = (st == qt);
        float mx[4];
        for (int r = 0; r < 4; r++) {
            for (int nt = 0; nt < 4; nt++) {
                float s = sacc[nt][r] * SCALE;
                if (diag) {
                    int sg = s0 + nt * 16 + ln16;
                    int qg = q0 + 16 * wv + quad * 4 + r;
                    if (sg > qg) s = -INFINITY;
                }
                sacc[nt][r] = s;
            }
            float m = fmaxf(fmaxf(sacc[0][r], sacc[1][r]), fmaxf(sacc[2][r], sacc[3][r]));
            mx[r] = m;
        }
        for (int off = 8; off >= 1; off >>= 1)
            for (int r = 0; r < 4; r++)
                mx[r] = fmaxf(mx[r], __shfl_xor(mx[r], off));

        float al[4];
        for (int r = 0; r < 4; r++) {
            float mnew = fmaxf(m_i[r], mx[r]);
            al[r] = __expf(m_i[r] - mnew);   // -inf first iter -> 0
            m_i[r] = mnew;
        }
        float rs[4];
        for (int r = 0; r < 4; r++) {
            float s = 0.f;
            for (int nt = 0; nt < 4; nt++) {
                float pv = __expf(sacc[nt][r] - m_i[r]);   // masked: exp(-inf)=0
                sacc[nt][r] = pv;
                s += pv;
            }
            rs[r] = s;
        }
        for (int off = 8; off >= 1; off >>= 1)
            for (int r = 0; r < 4; r++)
                rs[r] += __shfl_xor(rs[r], off);
        for (int r = 0; r < 4; r++) l_i[r] = l_i[r] * al[r] + rs[r];
        for (int nt = 0; nt < 8; nt++)
            for (int r = 0; r < 4; r++)
                o_acc[nt][r] *= al[r];

        // P -> LDS bf16 (wave writes only its own rows; reads only its own rows,
        // so no barrier needed — compiler inserts lgkmcnt for same-wave RAW)
        for (int nt = 0; nt < 4; nt++)
            for (int r = 0; r < 4; r++)
                Ps[(16 * wv + quad * 4 + r) * 72 + nt * 16 + ln16] = f2bf(sacc[nt][r]);

        // ---- O += P V ----
        for (int kc2 = 0; kc2 < 2; kc2++) {
            bf16x8 a = *(const bf16x8*)&Ps[(16 * wv + ln16) * 72 + kc2 * 32 + quad * 8];
            for (int nt = 0; nt < 8; nt++) {
                bf16x8 b = *(const bf16x8*)&Vs[(nt * 16 + ln16) * 72 + kc2 * 32 + quad * 8];
                o_acc[nt] = __builtin_amdgcn_mfma_f32_16x16x32_bf16(a, b, o_acc[nt], 0, 0, 0);
            }
        }
    }

    // epilogue: O / l, fp32 out [b][t][128]
    float inv[4];
    for (int r = 0; r < 4; r++) inv[r] = 1.f / l_i[r];
    for (int nt = 0; nt < 8; nt++)
        for (int r = 0; r < 4; r++)
            out[((size_t)bb * TT + q0 + 16 * wv + quad * 4 + r) * HD + nt * 16 + ln16] =
                o_acc[nt][r] * inv[r];
}

// ---------------------------------------------------------------------------
extern "C" void kernel_launch(void* const* d_in, const int* in_sizes, int n_in,
                              void* d_out, int out_size, void* d_ws, size_t ws_size,
                              hipStream_t stream) {
    const float* x  = (const float*)d_in[0];
    const float* Wq = (const float*)d_in[1];
    const float* bq = (const float*)d_in[2];
    const float* Wk = (const float*)d_in[3];
    const float* bk = (const float*)d_in[4];
    const float* Wv = (const float*)d_in[5];
    const float* bv = (const float*)d_in[6];
    float* out = (float*)d_out;

    // workspace layout (ushorts): x_bf16 | WT | Q | K | Vt  => ~81.3 MB total
    ushort* xbf = (ushort*)d_ws;
    ushort* WT  = xbf + (size_t)M_TOT * D_MODEL;
    ushort* Qb  = WT  + (size_t)3 * HD * D_MODEL;
    ushort* Kb  = Qb  + (size_t)M_TOT * HD;
    ushort* Vt  = Kb  + (size_t)M_TOT * HD;

    hipLaunchKernelGGL(cvt_x_kernel, dim3(4096), dim3(256), 0, stream, x, xbf);
    hipLaunchKernelGGL(wt_kernel, dim3(1024, 3), dim3(256), 0, stream, Wq, Wk, Wv, WT);
    hipLaunchKernelGGL(proj_kernel, dim3(128, 3), dim3(256), 0, stream,
                       xbf, WT, bq, bk, bv, Qb, Kb, Vt);
    hipLaunchKernelGGL(attn_kernel, dim3(64, NB), dim3(256), 0, stream, Qb, Kb, Vt, out);
}

// Round 2
// 385.995 us; speedup vs baseline: 1.2636x; 1.2636x over previous
//
#include <hip/hip_runtime.h>
#include <math.h>

// Problem constants
#define D_MODEL 2048
#define HD      128
#define NB      4
#define TT      4096
#define M_TOT   (NB * TT)   // 16384
#define NCH     160         // causal s-chunks per batch at BQ=64, 16 tiles/chunk
#define CHT     16          // s-tiles (of 64 keys) per chunk

typedef __attribute__((ext_vector_type(8))) short bf16x8;   // 8 bf16 = 4 VGPRs
typedef __attribute__((ext_vector_type(4))) float f32x4;

__device__ __forceinline__ ushort f2bf(float f) {
    union { float f; unsigned int u; } v; v.f = f;
    unsigned int u = v.u;
    unsigned int r = (u + 0x7FFFu + ((u >> 16) & 1u)) >> 16;   // RNE
    return (ushort)r;
}

// ---------------------------------------------------------------------------
// Kernel 1: WT[p][n][k] = bf16(W_p[k][n])  (transpose so B-frags are k-contiguous)
// ---------------------------------------------------------------------------
__global__ void wt_kernel(const float* __restrict__ Wq, const float* __restrict__ Wk,
                          const float* __restrict__ Wv, ushort* __restrict__ WT) {
    int p = blockIdx.y;
    const float* W = (p == 0) ? Wq : ((p == 1) ? Wk : Wv);
    int e = blockIdx.x * 256 + threadIdx.x;     // e over 128*2048
    int n = e & 127;                            // coalesced reads (n fastest)
    int k = e >> 7;
    WT[(size_t)p * (128 * 2048) + (size_t)n * 2048 + k] = f2bf(W[(size_t)k * 128 + n]);
}

// ---------------------------------------------------------------------------
// Kernel 2: fused QKV projection. Block = 64 rows x 384 cols (Q|K|V), 8 waves.
// x read ONCE as fp32, converted to bf16 during LDS staging (no cvt pre-pass).
// W tile staged in LDS per k-step (shared by all 8 waves -> no duplicated
// L2 fetch). Wave (rw=wv>>2, cw=wv&3) computes 32 rows x 96 cols = 2x6 tiles.
// V written transposed: Vt[b][h][t].
// ---------------------------------------------------------------------------
__global__ __launch_bounds__(512) void proj_fused(
        const float* __restrict__ x, const ushort* __restrict__ WT,
        const float* __restrict__ bq, const float* __restrict__ bk, const float* __restrict__ bv,
        ushort* __restrict__ Qb, ushort* __restrict__ Kb, ushort* __restrict__ Vt) {
    const int row0 = blockIdx.x * 64;

    __shared__ ushort As[64 * 40];    // [m][k] bf16, row stride 80B (odd multiple of 16B)
    __shared__ ushort Bs[384 * 40];   // [n][k] bf16

    const int tid  = threadIdx.x;
    const int lane = tid & 63;
    const int wv   = tid >> 6;        // 0..7
    const int rw   = wv >> 2;         // row half 0..1
    const int cw   = wv & 3;          // col quarter 0..3
    const int quad = lane >> 4;
    const int ln16 = lane & 15;

    f32x4 acc[2][6];
    for (int mt = 0; mt < 2; mt++)
        for (int nt = 0; nt < 6; nt++)
            acc[mt][nt] = (f32x4){0.f, 0.f, 0.f, 0.f};

    for (int k0 = 0; k0 < D_MODEL; k0 += 32) {
        __syncthreads();
        // stage A: 64x32 fp32 -> bf16. 512 float4 chunks, 1 per thread.
        {
            int row = tid >> 3, kc = tid & 7;
            float4 f = *(const float4*)(x + (size_t)(row0 + row) * D_MODEL + k0 + kc * 4);
            ushort4 o;
            o.x = f2bf(f.x); o.y = f2bf(f.y); o.z = f2bf(f.z); o.w = f2bf(f.w);
            *(ushort4*)&As[row * 40 + kc * 4] = o;
        }
        // stage B: 384x32 bf16 = 1536 16B chunks, 3 per thread.
        for (int i = 0; i < 3; i++) {
            int c = i * 512 + tid;
            int n = c >> 2, kc = c & 3;
            uint4 v = *(const uint4*)(WT + (size_t)n * 2048 + k0 + kc * 8);
            *(uint4*)&Bs[n * 40 + kc * 8] = v;
        }
        __syncthreads();

        bf16x8 a[2], b[6];
        for (int mt = 0; mt < 2; mt++)
            a[mt] = *(const bf16x8*)&As[(rw * 32 + mt * 16 + ln16) * 40 + quad * 8];
        for (int nt = 0; nt < 6; nt++)
            b[nt] = *(const bf16x8*)&Bs[(cw * 96 + nt * 16 + ln16) * 40 + quad * 8];
        for (int mt = 0; mt < 2; mt++)
            for (int nt = 0; nt < 6; nt++)
                acc[mt][nt] = __builtin_amdgcn_mfma_f32_16x16x32_bf16(a[mt], b[nt], acc[mt][nt], 0, 0, 0);
    }

    // Epilogue. C/D layout: col=lane&15, row=quad*4+reg.
    for (int nt = 0; nt < 6; nt++) {
        int col = cw * 96 + nt * 16 + ln16;   // 0..383; p uniform per n-tile
        int p = col >> 7;
        int h = col & 127;
        const float* bias = (p == 0) ? bq : ((p == 1) ? bk : bv);
        float bc = bias[h];
        for (int mt = 0; mt < 2; mt++) {
            int rbase = row0 + rw * 32 + mt * 16 + quad * 4;
            if (p < 2) {
                ushort* O = (p == 0) ? Qb : Kb;
                for (int r = 0; r < 4; r++)
                    O[(size_t)(rbase + r) * HD + h] = f2bf(acc[mt][nt][r] + bc);
            } else {
                int b = rbase >> 12;
                int t = rbase & 4095;
                ushort4 o;
                o.x = f2bf(acc[mt][nt][0] + bc);
                o.y = f2bf(acc[mt][nt][1] + bc);
                o.z = f2bf(acc[mt][nt][2] + bc);
                o.w = f2bf(acc[mt][nt][3] + bc);
                *(ushort4*)(Vt + ((size_t)b * HD + h) * TT + t) = o;
            }
        }
    }
}

// ---------------------------------------------------------------------------
// Kernel 3: split-s flash attention (partials). Block = one (b, qt, chunk):
// chunk covers s-tiles [ch*16, min(qt+1, ch*16+16)). 160 chunks/batch -> 640
// blocks, enumerated qt-DESCENDING (heavy chunks dispatch first, light ones
// backfill; 2 blocks/CU resident at 62KB LDS). Writes unnormalized O + (m,l).
// ---------------------------------------------------------------------------
#define SCALE 0.08838834764831845f   // 1/sqrt(128)

__global__ __launch_bounds__(256) void attn_part(
        const ushort* __restrict__ Qb, const ushort* __restrict__ Kb,
        const ushort* __restrict__ Vt, float* __restrict__ Opart,
        float* __restrict__ Mpart, float* __restrict__ Lpart) {
    const int blk = blockIdx.x;
    const int bb  = blk & 3;
    const int cid = blk >> 2;          // 0..159, ascending == qt descending

    // map cid -> (qt, ch): qt=63 gets chunks first. cnt(qt) = qt/16 + 1.
    int rem = cid, qt = 63;
    for (;;) {
        int cnt = (qt >> 4) + 1;
        if (rem < cnt) break;
        rem -= cnt; --qt;
    }
    const int ch    = rem;
    const int st_lo = ch * CHT;
    const int st_hi = min(qt + 1, st_lo + CHT);
    const int q0    = qt * 64;

    __shared__ ushort Qs[64 * 136];   // [q][h], stride 272B = 17*16B
    __shared__ ushort Ks[64 * 136];   // [s][h]
    __shared__ ushort Vs[128 * 72];   // [h][s], stride 144B = 9*16B
    __shared__ ushort Ps[64 * 72];    // [q][s]

    const int tid  = threadIdx.x;
    const int lane = tid & 63;
    const int wv   = tid >> 6;
    const int quad = lane >> 4;
    const int ln16 = lane & 15;

    // stage Q tile once
    for (int i = 0; i < 4; i++) {
        int c = i * 256 + tid;
        int row = c >> 4, kc = c & 15;
        uint4 v = *(const uint4*)(Qb + ((size_t)(bb * TT + q0 + row)) * HD + kc * 8);
        *(uint4*)&Qs[row * 136 + kc * 8] = v;
    }

    f32x4 o_acc[8];
    for (int nt = 0; nt < 8; nt++) o_acc[nt] = (f32x4){0.f, 0.f, 0.f, 0.f};
    float m_i[4], l_i[4];
    for (int r = 0; r < 4; r++) { m_i[r] = -INFINITY; l_i[r] = 0.f; }

    for (int st = st_lo; st < st_hi; st++) {
        const int s0 = st * 64;
        __syncthreads();   // Ks/Vs/Ps reuse (also covers Q staging on first iter)
        for (int i = 0; i < 4; i++) {
            int c = i * 256 + tid;
            int row = c >> 4, kc = c & 15;
            uint4 v = *(const uint4*)(Kb + ((size_t)(bb * TT + s0 + row)) * HD + kc * 8);
            *(uint4*)&Ks[row * 136 + kc * 8] = v;
        }
        for (int i = 0; i < 4; i++) {
            int c = i * 256 + tid;
            int h = c >> 3, sc = c & 7;
            uint4 v = *(const uint4*)(Vt + ((size_t)bb * HD + h) * TT + s0 + sc * 8);
            *(uint4*)&Vs[h * 72 + sc * 8] = v;
        }
        __syncthreads();

        // ---- S = Q K^T ----
        f32x4 sacc[4];
        for (int nt = 0; nt < 4; nt++) sacc[nt] = (f32x4){0.f, 0.f, 0.f, 0.f};
        for (int kc = 0; kc < 4; kc++) {
            bf16x8 a = *(const bf16x8*)&Qs[(16 * wv + ln16) * 136 + kc * 32 + quad * 8];
            for (int nt = 0; nt < 4; nt++) {
                bf16x8 b = *(const bf16x8*)&Ks[(nt * 16 + ln16) * 136 + kc * 32 + quad * 8];
                sacc[nt] = __builtin_amdgcn_mfma_f32_16x16x32_bf16(a, b, sacc[nt], 0, 0, 0);
            }
        }

        // ---- scale + causal mask + online softmax (rows wave-private) ----
        const bool diag = (st == qt);
        float mx[4];
        for (int r = 0; r < 4; r++) {
            for (int nt = 0; nt < 4; nt++) {
                float s = sacc[nt][r] * SCALE;
                if (diag) {
                    int sg = s0 + nt * 16 + ln16;
                    int qg = q0 + 16 * wv + quad * 4 + r;
                    if (sg > qg) s = -INFINITY;
                }
                sacc[nt][r] = s;
            }
            mx[r] = fmaxf(fmaxf(sacc[0][r], sacc[1][r]), fmaxf(sacc[2][r], sacc[3][r]));
        }
        for (int off = 8; off >= 1; off >>= 1)
            for (int r = 0; r < 4; r++)
                mx[r] = fmaxf(mx[r], __shfl_xor(mx[r], off));

        float al[4];
        for (int r = 0; r < 4; r++) {
            float mnew = fmaxf(m_i[r], mx[r]);
            al[r] = __expf(m_i[r] - mnew);
            m_i[r] = mnew;
        }
        float rs[4];
        for (int r = 0; r < 4; r++) {
            float s = 0.f;
            for (int nt = 0; nt < 4; nt++) {
                float pv = __expf(sacc[nt][r] - m_i[r]);
                sacc[nt][r] = pv;
                s += pv;
            }
            rs[r] = s;
        }
        for (int off = 8; off >= 1; off >>= 1)
            for (int r = 0; r < 4; r++)
                rs[r] += __shfl_xor(rs[r], off);
        for (int r = 0; r < 4; r++) l_i[r] = l_i[r] * al[r] + rs[r];
        for (int nt = 0; nt < 8; nt++)
            for (int r = 0; r < 4; r++)
                o_acc[nt][r] *= al[r];

        // P -> LDS bf16 (same-wave rows only; no barrier needed)
        for (int nt = 0; nt < 4; nt++)
            for (int r = 0; r < 4; r++)
                Ps[(16 * wv + quad * 4 + r) * 72 + nt * 16 + ln16] = f2bf(sacc[nt][r]);

        // ---- O += P V ----
        for (int kc2 = 0; kc2 < 2; kc2++) {
            bf16x8 a = *(const bf16x8*)&Ps[(16 * wv + ln16) * 72 + kc2 * 32 + quad * 8];
            for (int nt = 0; nt < 8; nt++) {
                bf16x8 b = *(const bf16x8*)&Vs[(nt * 16 + ln16) * 72 + kc2 * 32 + quad * 8];
                o_acc[nt] = __builtin_amdgcn_mfma_f32_16x16x32_bf16(a, b, o_acc[nt], 0, 0, 0);
            }
        }
    }

    // epilogue: unnormalized partial O + (m, l)
    const size_t slot = (size_t)bb * NCH + cid;
    for (int nt = 0; nt < 8; nt++)
        for (int r = 0; r < 4; r++)
            Opart[(slot * 64 + 16 * wv + quad * 4 + r) * HD + nt * 16 + ln16] = o_acc[nt][r];
    if (ln16 == 0)
        for (int r = 0; r < 4; r++) {
            Mpart[slot * 64 + 16 * wv + quad * 4 + r] = m_i[r];
            Lpart[slot * 64 + 16 * wv + quad * 4 + r] = l_i[r];
        }
}

// ---------------------------------------------------------------------------
// Kernel 4: merge partial chunks -> final output (fp32).
// ---------------------------------------------------------------------------
__global__ __launch_bounds__(256) void merge_kernel(
        const float* __restrict__ Opart, const float* __restrict__ Mpart,
        const float* __restrict__ Lpart, float* __restrict__ out) {
    const int qt = blockIdx.x;    // 0..63
    const int bb = blockIdx.y;
    const int nch = (qt >> 4) + 1;
    // base slot within batch: chunks are enumerated qt-descending
    int base = 0;
    for (int q = 63; q > qt; --q) base += (q >> 4) + 1;

    const int tid = threadIdx.x;
    const int q0  = qt * 64;
    // 64 rows x 32 float4 = 2048 elements; 8 per thread
    for (int e = tid; e < 64 * 32; e += 256) {
        int row = e >> 5;
        int c4  = e & 31;
        float M = -INFINITY;
        float mv[4];
        for (int ch = 0; ch < nch; ch++) {
            mv[ch] = Mpart[((size_t)bb * NCH + base + ch) * 64 + row];
            M = fmaxf(M, mv[ch]);
        }
        float L = 0.f;
        float w[4];
        for (int ch = 0; ch < nch; ch++) {
            w[ch] = __expf(mv[ch] - M);
            L += w[ch] * Lpart[((size_t)bb * NCH + base + ch) * 64 + row];
        }
        float4 acc = {0.f, 0.f, 0.f, 0.f};
        for (int ch = 0; ch < nch; ch++) {
            const float4 o = *(const float4*)(Opart +
                (((size_t)bb * NCH + base + ch) * 64 + row) * HD + c4 * 4);
            acc.x += w[ch] * o.x; acc.y += w[ch] * o.y;
            acc.z += w[ch] * o.z; acc.w += w[ch] * o.w;
        }
        float invL = 1.f / L;
        float4 res = {acc.x * invL, acc.y * invL, acc.z * invL, acc.w * invL};
        *(float4*)(out + ((size_t)bb * TT + q0 + row) * HD + c4 * 4) = res;
    }
}

// ---------------------------------------------------------------------------
extern "C" void kernel_launch(void* const* d_in, const int* in_sizes, int n_in,
                              void* d_out, int out_size, void* d_ws, size_t ws_size,
                              hipStream_t stream) {
    const float* x  = (const float*)d_in[0];
    const float* Wq = (const float*)d_in[1];
    const float* bq = (const float*)d_in[2];
    const float* Wk = (const float*)d_in[3];
    const float* bk = (const float*)d_in[4];
    const float* Wv = (const float*)d_in[5];
    const float* bv = (const float*)d_in[6];
    float* out = (float*)d_out;

    // workspace layout: WT | Qb | Kb | Vt (bf16) | Opart | Mpart | Lpart (fp32)
    ushort* WT = (ushort*)d_ws;
    ushort* Qb = WT + (size_t)3 * HD * D_MODEL;
    ushort* Kb = Qb + (size_t)M_TOT * HD;
    ushort* Vt = Kb + (size_t)M_TOT * HD;
    float* Opart = (float*)(Vt + (size_t)M_TOT * HD);
    float* Mpart = Opart + (size_t)NB * NCH * 64 * HD;
    float* Lpart = Mpart + (size_t)NB * NCH * 64;

    hipLaunchKernelGGL(wt_kernel, dim3(1024, 3), dim3(256), 0, stream, Wq, Wk, Wv, WT);
    hipLaunchKernelGGL(proj_fused, dim3(256), dim3(512), 0, stream,
                       x, WT, bq, bk, bv, Qb, Kb, Vt);
    hipLaunchKernelGGL(attn_part, dim3(NB * NCH), dim3(256), 0, stream,
                       Qb, Kb, Vt, Opart, Mpart, Lpart);
    hipLaunchKernelGGL(merge_kernel, dim3(64, NB), dim3(256), 0, stream,
                       Opart, Mpart, Lpart, out);
}

// Round 3
// 332.546 us; speedup vs baseline: 1.4667x; 1.1607x over previous
//
#include <hip/hip_runtime.h>
#include <math.h>

// Problem constants
#define D_MODEL 2048
#define HD      128
#define NB      4
#define TT      4096
#define M_TOT   (NB * TT)   // 16384
#define NCH     160         // causal s-chunks per batch at BQ=64, 16 tiles/chunk
#define CHT     16          // s-tiles (of 64 keys) per chunk

typedef __attribute__((ext_vector_type(8))) short bf16x8;   // 8 bf16 = 4 VGPRs
typedef __attribute__((ext_vector_type(4))) float f32x4;

__device__ __forceinline__ ushort f2bf(float f) {
    union { float f; unsigned int u; } v; v.f = f;
    unsigned int u = v.u;
    unsigned int r = (u + 0x7FFFu + ((u >> 16) & 1u)) >> 16;   // RNE
    return (ushort)r;
}

// async global->LDS DMA, 16B per lane. LDS dst = wave-uniform base + lane*16.
__device__ __forceinline__ void gload_lds16(const void* g, void* l) {
    __builtin_amdgcn_global_load_lds(
        (const __attribute__((address_space(1))) unsigned int*)g,
        (__attribute__((address_space(3))) unsigned int*)l, 16, 0, 0);
}

// ---------------------------------------------------------------------------
// Kernel 1: WT[p][n][k] = bf16(W_p[k][n])
// ---------------------------------------------------------------------------
__global__ void wt_kernel(const float* __restrict__ Wq, const float* __restrict__ Wk,
                          const float* __restrict__ Wv, ushort* __restrict__ WT) {
    int p = blockIdx.y;
    const float* W = (p == 0) ? Wq : ((p == 1) ? Wk : Wv);
    int e = blockIdx.x * 256 + threadIdx.x;
    int n = e & 127;
    int k = e >> 7;
    WT[(size_t)p * (128 * 2048) + (size_t)n * 2048 + k] = f2bf(W[(size_t)k * 128 + n]);
}

// ---------------------------------------------------------------------------
// Kernel 2: fused QKV projection. Grid 512: m-tile (64 rows) x col-half (192).
// B staged via global_load_lds (swizzled, unpadded); A prefetched into VGPRs
// one k-step ahead (fp32->bf16 cvt at LDS-write time). 2 blocks/CU.
// ---------------------------------------------------------------------------
__global__ __launch_bounds__(256) void proj_fused(
        const float* __restrict__ x, const ushort* __restrict__ WT,
        const float* __restrict__ bq, const float* __restrict__ bk, const float* __restrict__ bv,
        ushort* __restrict__ Qb, ushort* __restrict__ Kb, ushort* __restrict__ Vt) {
    const int bx   = blockIdx.x;
    const int row0 = (bx >> 1) * 64;
    const int col0 = (bx & 1) * 192;

    __shared__ ushort As[64 * 40];    // [m][k], stride 80B (odd 16B multiple, conflict-free)
    __shared__ ushort Bs[192 * 32];   // [n][k] unpadded, XOR-swizzled: phys kc = kc ^ ((n>>1)&3)

    const int tid  = threadIdx.x;
    const int lane = tid & 63;
    const int wv   = tid >> 6;        // 0..3
    const int rw   = wv >> 1;         // row half
    const int cw   = wv & 1;          // col half (96 cols)
    const int quad = lane >> 4;
    const int ln16 = lane & 15;

    // B DMA: 768 chunks of 16B, 3 per thread. Source pre-swizzled per thread.
    size_t  boff[3];
    ushort* bdst[3];
    for (int i = 0; i < 3; i++) {
        int c = i * 256 + tid;
        int n = c >> 2, j = c & 3;
        int kc = j ^ ((n >> 1) & 3);
        boff[i] = (size_t)(col0 + n) * 2048 + kc * 8;
        bdst[i] = &Bs[(i * 256 + wv * 64) * 8];   // wave-uniform base
    }
    // A chunks: 512 float4, 2 per thread
    int arow[2], acol[2];
    for (int j = 0; j < 2; j++) {
        int c = j * 256 + tid;
        arow[j] = c >> 3;
        acol[j] = (c & 7) * 4;
    }

    f32x4 acc[2][6];
    for (int m2 = 0; m2 < 2; m2++)
        for (int nt = 0; nt < 6; nt++)
            acc[m2][nt] = (f32x4){0.f, 0.f, 0.f, 0.f};

    float4 areg[2];
    for (int j = 0; j < 2; j++)
        areg[j] = *(const float4*)(x + (size_t)(row0 + arow[j]) * D_MODEL + acol[j]);

    for (int k0 = 0; k0 < D_MODEL; k0 += 32) {
        __syncthreads();   // previous compute done reading LDS
        for (int i = 0; i < 3; i++)
            gload_lds16(WT + boff[i] + k0, bdst[i]);
        for (int j = 0; j < 2; j++) {
            ushort4 o;
            o.x = f2bf(areg[j].x); o.y = f2bf(areg[j].y);
            o.z = f2bf(areg[j].z); o.w = f2bf(areg[j].w);
            *(ushort4*)&As[arow[j] * 40 + acol[j]] = o;
        }
        __syncthreads();   // drains DMA (vmcnt) + A writes (lgkm)
        if (k0 + 32 < D_MODEL)   // prefetch next A tile; latency hidden by MFMA phase
            for (int j = 0; j < 2; j++)
                areg[j] = *(const float4*)(x + (size_t)(row0 + arow[j]) * D_MODEL + k0 + 32 + acol[j]);

        bf16x8 a[2], b[6];
        for (int m2 = 0; m2 < 2; m2++)
            a[m2] = *(const bf16x8*)&As[(rw * 32 + m2 * 16 + ln16) * 40 + quad * 8];
        for (int nt = 0; nt < 6; nt++) {
            int n = cw * 96 + nt * 16 + ln16;
            b[nt] = *(const bf16x8*)&Bs[n * 32 + (quad ^ ((n >> 1) & 3)) * 8];
        }
        for (int m2 = 0; m2 < 2; m2++)
            for (int nt = 0; nt < 6; nt++)
                acc[m2][nt] = __builtin_amdgcn_mfma_f32_16x16x32_bf16(a[m2], b[nt], acc[m2][nt], 0, 0, 0);
    }

    // Epilogue. C/D: col=lane&15, row=quad*4+reg.
    for (int nt = 0; nt < 6; nt++) {
        int col = col0 + cw * 96 + nt * 16 + ln16;   // 0..383
        int p = col >> 7;
        int h = col & 127;
        const float* bias = (p == 0) ? bq : ((p == 1) ? bk : bv);
        float bc = bias[h];
        for (int m2 = 0; m2 < 2; m2++) {
            int rbase = row0 + rw * 32 + m2 * 16 + quad * 4;
            if (p < 2) {
                ushort* O = (p == 0) ? Qb : Kb;
                for (int r = 0; r < 4; r++)
                    O[(size_t)(rbase + r) * HD + h] = f2bf(acc[m2][nt][r] + bc);
            } else {
                int b = rbase >> 12;
                int t = rbase & 4095;
                ushort4 o;
                o.x = f2bf(acc[m2][nt][0] + bc);
                o.y = f2bf(acc[m2][nt][1] + bc);
                o.z = f2bf(acc[m2][nt][2] + bc);
                o.w = f2bf(acc[m2][nt][3] + bc);
                *(ushort4*)(Vt + ((size_t)b * HD + h) * TT + t) = o;
            }
        }
    }
}

// ---------------------------------------------------------------------------
// Kernel 3: split-s flash attention partials. 640 blocks (qt-descending).
// Q frags in registers; K/V via global_load_lds into XOR-swizzled LDS;
// Ps swizzled. LDS = exactly 40 KB -> 4 blocks/CU.
// ---------------------------------------------------------------------------
#define SCALE 0.08838834764831845f   // 1/sqrt(128)

__global__ __launch_bounds__(256, 4) void attn_part(
        const ushort* __restrict__ Qb, const ushort* __restrict__ Kb,
        const ushort* __restrict__ Vt, float* __restrict__ Opart,
        float* __restrict__ Mpart, float* __restrict__ Lpart) {
    const int blk = blockIdx.x;
    const int bb  = blk & 3;
    const int cid = blk >> 2;          // ascending == qt descending (heavy first)

    int rem = cid, qt = 63;
    for (;;) {
        int cnt = (qt >> 4) + 1;
        if (rem < cnt) break;
        rem -= cnt; --qt;
    }
    const int ch    = rem;
    const int st_lo = ch * CHT;
    const int st_hi = min(qt + 1, st_lo + CHT);
    const int q0    = qt * 64;

    __shared__ ushort Ks[64 * 128];   // [s][h] unpadded; phys chunk = kc ^ (s&15)
    __shared__ ushort Vs[128 * 64];   // [h][s] unpadded; phys chunk = kc ^ (h&7)
    __shared__ ushort Ps[64 * 64];    // [q][s] unpadded; phys chunk = kc ^ (q&7)

    const int tid  = threadIdx.x;
    const int lane = tid & 63;
    const int wv   = tid >> 6;
    const int quad = lane >> 4;
    const int ln16 = lane & 15;
    const int sw8  = ln16 & 7;

    // Q fragments straight into registers (wave-private rows)
    bf16x8 qf[4];
    {
        const ushort* qrow = Qb + (size_t)(bb * TT + q0 + 16 * wv + ln16) * HD;
        for (int kc = 0; kc < 4; kc++)
            qf[kc] = *(const bf16x8*)(qrow + kc * 32 + quad * 8);
    }

    // DMA plans: K 1024 chunks, V 1024 chunks, 4 each per thread
    int koff[4], voff[4];
    ushort *kdst[4], *vdst[4];
    for (int i = 0; i < 4; i++) {
        int c = i * 256 + tid;
        { int r = c >> 4, j = c & 15, kc = j ^ (r & 15);
          koff[i] = r * HD + kc * 8; }
        { int h = c >> 3, j = c & 7, kc = j ^ (h & 7);
          voff[i] = h * TT + kc * 8; }
        kdst[i] = &Ks[(i * 256 + wv * 64) * 8];
        vdst[i] = &Vs[(i * 256 + wv * 64) * 8];
    }

    f32x4 o_acc[8];
    for (int nt = 0; nt < 8; nt++) o_acc[nt] = (f32x4){0.f, 0.f, 0.f, 0.f};
    float m_i[4], l_i[4];
    for (int r = 0; r < 4; r++) { m_i[r] = -INFINITY; l_i[r] = 0.f; }

    for (int st = st_lo; st < st_hi; st++) {
        const int s0 = st * 64;
        __syncthreads();   // Ks/Vs free
        const ushort* kbase = Kb + ((size_t)bb * TT + s0) * HD;
        const ushort* vbase = Vt + (size_t)bb * HD * TT + s0;
        for (int i = 0; i < 4; i++) gload_lds16(kbase + koff[i], kdst[i]);
        for (int i = 0; i < 4; i++) gload_lds16(vbase + voff[i], vdst[i]);
        __syncthreads();   // drains DMA

        // ---- S = Q K^T ----
        f32x4 sacc[4];
        for (int nt = 0; nt < 4; nt++) sacc[nt] = (f32x4){0.f, 0.f, 0.f, 0.f};
        for (int kc = 0; kc < 4; kc++) {
            int lc = kc * 4 + quad;   // logical 16B chunk 0..15
            for (int nt = 0; nt < 4; nt++) {
                int r = nt * 16 + ln16;
                bf16x8 b = *(const bf16x8*)&Ks[r * 128 + (lc ^ ln16) * 8];
                sacc[nt] = __builtin_amdgcn_mfma_f32_16x16x32_bf16(qf[kc], b, sacc[nt], 0, 0, 0);
            }
        }

        // ---- scale + causal mask + online softmax (rows wave-private) ----
        const bool diag = (st == qt);
        float mx[4];
        for (int r = 0; r < 4; r++) {
            for (int nt = 0; nt < 4; nt++) {
                float s = sacc[nt][r] * SCALE;
                if (diag) {
                    int sg = s0 + nt * 16 + ln16;
                    int qg = q0 + 16 * wv + quad * 4 + r;
                    if (sg > qg) s = -INFINITY;
                }
                sacc[nt][r] = s;
            }
            mx[r] = fmaxf(fmaxf(sacc[0][r], sacc[1][r]), fmaxf(sacc[2][r], sacc[3][r]));
        }
        for (int off = 8; off >= 1; off >>= 1)
            for (int r = 0; r < 4; r++)
                mx[r] = fmaxf(mx[r], __shfl_xor(mx[r], off));

        float al[4];
        for (int r = 0; r < 4; r++) {
            float mnew = fmaxf(m_i[r], mx[r]);
            al[r] = __expf(m_i[r] - mnew);
            m_i[r] = mnew;
        }
        float rs[4];
        for (int r = 0; r < 4; r++) {
            float s = 0.f;
            for (int nt = 0; nt < 4; nt++) {
                float pv = __expf(sacc[nt][r] - m_i[r]);
                sacc[nt][r] = pv;
                s += pv;
            }
            rs[r] = s;
        }
        for (int off = 8; off >= 1; off >>= 1)
            for (int r = 0; r < 4; r++)
                rs[r] += __shfl_xor(rs[r], off);
        for (int r = 0; r < 4; r++) l_i[r] = l_i[r] * al[r] + rs[r];
        for (int nt = 0; nt < 8; nt++)
            for (int r = 0; r < 4; r++)
                o_acc[nt][r] *= al[r];

        // P -> LDS (swizzled; same-wave rows only, no barrier needed)
        for (int nt = 0; nt < 4; nt++)
            for (int r = 0; r < 4; r++) {
                int row = 16 * wv + quad * 4 + r;
                int cj  = nt * 2 + (ln16 >> 3);          // col>>3
                Ps[row * 64 + ((cj ^ (row & 7)) * 8) + sw8] = f2bf(sacc[nt][r]);
            }

        // ---- O += P V ----
        for (int kc2 = 0; kc2 < 2; kc2++) {
            int lc = kc2 * 4 + quad;   // logical chunk 0..7
            int prow = 16 * wv + ln16;
            bf16x8 a = *(const bf16x8*)&Ps[prow * 64 + ((lc ^ sw8) * 8)];
            for (int nt = 0; nt < 8; nt++) {
                int h = nt * 16 + ln16;
                bf16x8 b = *(const bf16x8*)&Vs[h * 64 + ((lc ^ sw8) * 8)];
                o_acc[nt] = __builtin_amdgcn_mfma_f32_16x16x32_bf16(a, b, o_acc[nt], 0, 0, 0);
            }
        }
    }

    // epilogue: unnormalized partial O + (m, l)
    const size_t slot = (size_t)bb * NCH + cid;
    for (int nt = 0; nt < 8; nt++)
        for (int r = 0; r < 4; r++)
            Opart[(slot * 64 + 16 * wv + quad * 4 + r) * HD + nt * 16 + ln16] = o_acc[nt][r];
    if (ln16 == 0)
        for (int r = 0; r < 4; r++) {
            Mpart[slot * 64 + 16 * wv + quad * 4 + r] = m_i[r];
            Lpart[slot * 64 + 16 * wv + quad * 4 + r] = l_i[r];
        }
}

// ---------------------------------------------------------------------------
// Kernel 4: merge partial chunks -> final output (fp32).
// ---------------------------------------------------------------------------
__global__ __launch_bounds__(256) void merge_kernel(
        const float* __restrict__ Opart, const float* __restrict__ Mpart,
        const float* __restrict__ Lpart, float* __restrict__ out) {
    const int qt = blockIdx.x;
    const int bb = blockIdx.y;
    const int nch = (qt >> 4) + 1;
    int base = 0;
    for (int q = 63; q > qt; --q) base += (q >> 4) + 1;

    const int tid = threadIdx.x;
    const int q0  = qt * 64;
    for (int e = tid; e < 64 * 32; e += 256) {
        int row = e >> 5;
        int c4  = e & 31;
        float M = -INFINITY;
        float mv[4];
        for (int ch = 0; ch < nch; ch++) {
            mv[ch] = Mpart[((size_t)bb * NCH + base + ch) * 64 + row];
            M = fmaxf(M, mv[ch]);
        }
        float L = 0.f;
        float w[4];
        for (int ch = 0; ch < nch; ch++) {
            w[ch] = __expf(mv[ch] - M);
            L += w[ch] * Lpart[((size_t)bb * NCH + base + ch) * 64 + row];
        }
        float4 acc = {0.f, 0.f, 0.f, 0.f};
        for (int ch = 0; ch < nch; ch++) {
            const float4 o = *(const float4*)(Opart +
                (((size_t)bb * NCH + base + ch) * 64 + row) * HD + c4 * 4);
            acc.x += w[ch] * o.x; acc.y += w[ch] * o.y;
            acc.z += w[ch] * o.z; acc.w += w[ch] * o.w;
        }
        float invL = 1.f / L;
        float4 res = {acc.x * invL, acc.y * invL, acc.z * invL, acc.w * invL};
        *(float4*)(out + ((size_t)bb * TT + q0 + row) * HD + c4 * 4) = res;
    }
}

// ---------------------------------------------------------------------------
extern "C" void kernel_launch(void* const* d_in, const int* in_sizes, int n_in,
                              void* d_out, int out_size, void* d_ws, size_t ws_size,
                              hipStream_t stream) {
    const float* x  = (const float*)d_in[0];
    const float* Wq = (const float*)d_in[1];
    const float* bq = (const float*)d_in[2];
    const float* Wk = (const float*)d_in[3];
    const float* bk = (const float*)d_in[4];
    const float* Wv = (const float*)d_in[5];
    const float* bv = (const float*)d_in[6];
    float* out = (float*)d_out;

    ushort* WT = (ushort*)d_ws;
    ushort* Qb = WT + (size_t)3 * HD * D_MODEL;
    ushort* Kb = Qb + (size_t)M_TOT * HD;
    ushort* Vt = Kb + (size_t)M_TOT * HD;
    float* Opart = (float*)(Vt + (size_t)M_TOT * HD);
    float* Mpart = Opart + (size_t)NB * NCH * 64 * HD;
    float* Lpart = Mpart + (size_t)NB * NCH * 64;

    hipLaunchKernelGGL(wt_kernel, dim3(1024, 3), dim3(256), 0, stream, Wq, Wk, Wv, WT);
    hipLaunchKernelGGL(proj_fused, dim3(512), dim3(256), 0, stream,
                       x, WT, bq, bk, bv, Qb, Kb, Vt);
    hipLaunchKernelGGL(attn_part, dim3(NB * NCH), dim3(256), 0, stream,
                       Qb, Kb, Vt, Opart, Mpart, Lpart);
    hipLaunchKernelGGL(merge_kernel, dim3(64, NB), dim3(256), 0, stream,
                       Opart, Mpart, Lpart, out);
}

// Round 5
// 332.204 us; speedup vs baseline: 1.4682x; 1.0010x over previous
//
#include <hip/hip_runtime.h>
#include <math.h>

// Problem constants
#define D_MODEL 2048
#define HD      128
#define NB      4
#define TT      4096
#define M_TOT   (NB * TT)   // 16384
#define NCH     160         // causal s-chunks per batch at BQ=64, 16 tiles/chunk
#define CHT     16          // s-tiles (of 64 keys) per chunk

typedef __attribute__((ext_vector_type(8))) short bf16x8;   // 8 bf16 = 4 VGPRs
typedef __attribute__((ext_vector_type(4))) float f32x4;

__device__ __forceinline__ ushort f2bf(float f) {
    union { float f; unsigned int u; } v; v.f = f;
    unsigned int u = v.u;
    unsigned int r = (u + 0x7FFFu + ((u >> 16) & 1u)) >> 16;   // RNE
    return (ushort)r;
}

// async global->LDS DMA, 16B per lane. LDS dst = wave-uniform base + lane*16.
__device__ __forceinline__ void gload_lds16(const void* g, void* l) {
    __builtin_amdgcn_global_load_lds(
        (const __attribute__((address_space(1))) unsigned int*)g,
        (__attribute__((address_space(3))) unsigned int*)l, 16, 0, 0);
}

// ---------------------------------------------------------------------------
// Kernel 1: WT[p][n][k] = bf16(W_p[k][n]) via LDS tile transpose.
// Reads coalesced (n fastest); writes 256B runs per n-row.
// (Round-4 bug: write-back covered only j<8 of 16 chunks -> half of WT was
//  poison. Fixed: 2048 chunks, i<8, j=c&15.)
// ---------------------------------------------------------------------------
__global__ __launch_bounds__(256) void wt_kernel(
        const float* __restrict__ Wq, const float* __restrict__ Wk,
        const float* __restrict__ Wv, ushort* __restrict__ WT) {
    const int p  = blockIdx.y;
    const int k0 = blockIdx.x * 128;
    const float* W = (p == 0) ? Wq : ((p == 1) ? Wk : Wv);

    __shared__ ushort Ts[128 * 136];   // [n][kk], stride 272B (16B-aligned rows)

    const int tid = threadIdx.x;
    for (int i = 0; i < 64; i++) {
        int c  = i * 256 + tid;
        int kk = c >> 7, n = c & 127;
        Ts[n * 136 + kk] = f2bf(W[(size_t)(k0 + kk) * 128 + n]);
    }
    __syncthreads();
    for (int i = 0; i < 8; i++) {
        int c = i * 256 + tid;
        int n = c >> 4, j = c & 15;
        *(uint4*)(WT + (size_t)p * (128 * 2048) + (size_t)n * 2048 + k0 + j * 8) =
            *(const uint4*)&Ts[n * 136 + j * 8];
    }
}

// ---------------------------------------------------------------------------
// Kernel 2: fused QKV projection, macro-pipelined.
// Grid 512: (m-tile 64 rows) x (col-half 192). Macro k-step = 128 (x rows
// read as 512B contiguous -> DRAM-efficient), 4 micro BK=32 MFMA phases.
// B DMA'd per macro (L2-resident WT, 256B/row); A staged from register
// prefetch. LDS 65.4KB -> 2 blocks/CU.
// ---------------------------------------------------------------------------
__global__ __launch_bounds__(256, 2) void proj_fused(
        const float* __restrict__ x, const ushort* __restrict__ WT,
        const float* __restrict__ bq, const float* __restrict__ bk, const float* __restrict__ bv,
        ushort* __restrict__ Qb, ushort* __restrict__ Kb, ushort* __restrict__ Vt) {
    const int bx   = blockIdx.x;
    const int row0 = (bx >> 1) * 64;
    const int col0 = (bx & 1) * 192;

    __shared__ ushort As[64 * 136];    // [m][k0..k0+128), stride 272B (17x16B)
    __shared__ ushort Bs[192 * 128];   // [n][k] unpadded; slot j holds chunk j^(n&15)

    const int tid  = threadIdx.x;
    const int lane = tid & 63;
    const int wv   = tid >> 6;        // 0..3
    const int rw   = wv >> 1;         // row half (32 rows)
    const int cw   = wv & 1;          // col half (96 cols)
    const int quad = lane >> 4;
    const int ln16 = lane & 15;

    // B DMA plan: 3072 chunks of 16B per macro, 12 per thread
    size_t  boff[12];
    ushort* bdst[12];
    for (int i = 0; i < 12; i++) {
        int c = i * 256 + tid;
        int n = c >> 4, j = c & 15;
        int kc = j ^ (n & 15);
        boff[i] = (size_t)(col0 + n) * 2048 + kc * 8;
        bdst[i] = &Bs[(i * 256 + wv * 64) * 8];   // wave-uniform base
    }
    // A plan: 2048 float4 per macro, 8 per thread (rows read as 512B runs)
    int arow[8], apos[8];
    for (int i = 0; i < 8; i++) {
        int c = i * 256 + tid;
        arow[i] = c >> 5;
        apos[i] = c & 31;
    }

    f32x4 acc[2][6];
    for (int m2 = 0; m2 < 2; m2++)
        for (int nt = 0; nt < 6; nt++)
            acc[m2][nt] = (f32x4){0.f, 0.f, 0.f, 0.f};

    float4 areg[8];
    for (int i = 0; i < 8; i++)
        areg[i] = *(const float4*)(x + (size_t)(row0 + arow[i]) * D_MODEL + apos[i] * 4);

    for (int k0 = 0; k0 < D_MODEL; k0 += 128) {
        __syncthreads();   // all waves done reading As/Bs of previous macro
        for (int i = 0; i < 12; i++)
            gload_lds16(WT + boff[i] + k0, bdst[i]);
        for (int i = 0; i < 8; i++) {
            ushort4 o;
            o.x = f2bf(areg[i].x); o.y = f2bf(areg[i].y);
            o.z = f2bf(areg[i].z); o.w = f2bf(areg[i].w);
            *(ushort4*)&As[arow[i] * 136 + apos[i] * 4] = o;
        }
        __syncthreads();   // drain DMA (vm) + As writes (lgkm)
        if (k0 + 128 < D_MODEL)   // prefetch next macro's A (hidden by micro loop)
            for (int i = 0; i < 8; i++)
                areg[i] = *(const float4*)(x + (size_t)(row0 + arow[i]) * D_MODEL
                                             + k0 + 128 + apos[i] * 4);

        for (int mi = 0; mi < 4; mi++) {
            bf16x8 a[2], b[6];
            for (int m2 = 0; m2 < 2; m2++)
                a[m2] = *(const bf16x8*)&As[(rw * 32 + m2 * 16 + ln16) * 136 + mi * 32 + quad * 8];
            for (int nt = 0; nt < 6; nt++) {
                int n = cw * 96 + nt * 16 + ln16;
                int slot = (mi * 4 + quad) ^ (n & 15);
                b[nt] = *(const bf16x8*)&Bs[n * 128 + slot * 8];
            }
            for (int m2 = 0; m2 < 2; m2++)
                for (int nt = 0; nt < 6; nt++)
                    acc[m2][nt] = __builtin_amdgcn_mfma_f32_16x16x32_bf16(a[m2], b[nt], acc[m2][nt], 0, 0, 0);
        }
    }

    // Epilogue. C/D: col=lane&15, row=quad*4+reg.
    for (int nt = 0; nt < 6; nt++) {
        int col = col0 + cw * 96 + nt * 16 + ln16;   // 0..383
        int p = col >> 7;
        int h = col & 127;
        const float* bias = (p == 0) ? bq : ((p == 1) ? bk : bv);
        float bc = bias[h];
        for (int m2 = 0; m2 < 2; m2++) {
            int rbase = row0 + rw * 32 + m2 * 16 + quad * 4;
            if (p < 2) {
                ushort* O = (p == 0) ? Qb : Kb;
                for (int r = 0; r < 4; r++)
                    O[(size_t)(rbase + r) * HD + h] = f2bf(acc[m2][nt][r] + bc);
            } else {
                int b = rbase >> 12;
                int t = rbase & 4095;
                ushort4 o;
                o.x = f2bf(acc[m2][nt][0] + bc);
                o.y = f2bf(acc[m2][nt][1] + bc);
                o.z = f2bf(acc[m2][nt][2] + bc);
                o.w = f2bf(acc[m2][nt][3] + bc);
                *(ushort4*)(Vt + ((size_t)b * HD + h) * TT + t) = o;
            }
        }
    }
}

// ---------------------------------------------------------------------------
// Kernel 3: split-s flash attention partials, double-buffered K/V pipeline:
// DMA for tile t+1 issued BEFORE computing tile t; the single barrier per
// tile drains a load that had the whole compute phase to land.
// LDS 72KB -> 2 blocks/CU. 640 blocks, heavy (long-chunk) first.
// ---------------------------------------------------------------------------
#define SCALE 0.08838834764831845f   // 1/sqrt(128)

__global__ __launch_bounds__(256, 2) void attn_part(
        const ushort* __restrict__ Qb, const ushort* __restrict__ Kb,
        const ushort* __restrict__ Vt, float* __restrict__ Opart,
        float* __restrict__ Mpart, float* __restrict__ Lpart) {
    const int blk = blockIdx.x;
    const int bb  = blk & 3;
    const int cid = blk >> 2;          // ascending == qt descending (heavy first)

    int rem = cid, qt = 63;
    for (;;) {
        int cnt = (qt >> 4) + 1;
        if (rem < cnt) break;
        rem -= cnt; --qt;
    }
    const int ch    = rem;
    const int st_lo = ch * CHT;
    const int st_hi = min(qt + 1, st_lo + CHT);
    const int q0    = qt * 64;

    __shared__ ushort Ks[2][64 * 128];   // [s][h]; slot j holds chunk j^(s&15)
    __shared__ ushort Vs[2][128 * 64];   // [h][s]; slot j holds chunk j^(h&7)
    __shared__ ushort Ps[64 * 64];       // [q][s]; slot j holds chunk j^(q&7)

    const int tid  = threadIdx.x;
    const int lane = tid & 63;
    const int wv   = tid >> 6;
    const int quad = lane >> 4;
    const int ln16 = lane & 15;
    const int sw8  = ln16 & 7;

    // DMA plans: K 1024 chunks, V 1024 chunks, 4 each per thread
    int koff[4], voff[4], ldso[4];
    for (int i = 0; i < 4; i++) {
        int c = i * 256 + tid;
        { int r = c >> 4, j = c & 15, kc = j ^ (r & 15);
          koff[i] = r * HD + kc * 8; }
        { int h = c >> 3, j = c & 7, kc = j ^ (h & 7);
          voff[i] = h * TT + kc * 8; }
        ldso[i] = (i * 256 + wv * 64) * 8;    // wave-uniform LDS chunk base
    }
    const ushort* kbase = Kb + (size_t)bb * TT * HD;
    const ushort* vbase = Vt + (size_t)bb * HD * TT;

    // prologue: DMA first tile into buf 0; Q frags into registers meanwhile
    {
        const int s0 = st_lo * 64;
        for (int i = 0; i < 4; i++) gload_lds16(kbase + (size_t)s0 * HD + koff[i], &Ks[0][ldso[i]]);
        for (int i = 0; i < 4; i++) gload_lds16(vbase + s0 + voff[i], &Vs[0][ldso[i]]);
    }
    bf16x8 qf[4];
    {
        const ushort* qrow = Qb + (size_t)(bb * TT + q0 + 16 * wv + ln16) * HD;
        for (int kc = 0; kc < 4; kc++)
            qf[kc] = *(const bf16x8*)(qrow + kc * 32 + quad * 8);
    }

    f32x4 o_acc[8];
    for (int nt = 0; nt < 8; nt++) o_acc[nt] = (f32x4){0.f, 0.f, 0.f, 0.f};
    float m_i[4], l_i[4];
    for (int r = 0; r < 4; r++) { m_i[r] = -INFINITY; l_i[r] = 0.f; }

    __syncthreads();   // first tile's DMA drained

    for (int st = st_lo; st < st_hi; st++) {
        const int s0  = st * 64;
        const int buf = (st - st_lo) & 1;

        // issue next tile's DMA into the other buffer BEFORE computing
        if (st + 1 < st_hi) {
            const int s1 = s0 + 64;
            for (int i = 0; i < 4; i++) gload_lds16(kbase + (size_t)s1 * HD + koff[i], &Ks[buf ^ 1][ldso[i]]);
            for (int i = 0; i < 4; i++) gload_lds16(vbase + s1 + voff[i], &Vs[buf ^ 1][ldso[i]]);
        }

        // ---- S = Q K^T ----
        f32x4 sacc[4];
        for (int nt = 0; nt < 4; nt++) sacc[nt] = (f32x4){0.f, 0.f, 0.f, 0.f};
        for (int kc = 0; kc < 4; kc++) {
            int lc = kc * 4 + quad;
            for (int nt = 0; nt < 4; nt++) {
                int r = nt * 16 + ln16;
                bf16x8 b = *(const bf16x8*)&Ks[buf][r * 128 + ((lc ^ ln16) * 8)];
                sacc[nt] = __builtin_amdgcn_mfma_f32_16x16x32_bf16(qf[kc], b, sacc[nt], 0, 0, 0);
            }
        }

        // ---- scale + causal mask + online softmax (rows wave-private) ----
        const bool diag = (st == qt);
        float mx[4];
        for (int r = 0; r < 4; r++) {
            for (int nt = 0; nt < 4; nt++) {
                float s = sacc[nt][r] * SCALE;
                if (diag) {
                    int sg = s0 + nt * 16 + ln16;
                    int qg = q0 + 16 * wv + quad * 4 + r;
                    if (sg > qg) s = -INFINITY;
                }
                sacc[nt][r] = s;
            }
            mx[r] = fmaxf(fmaxf(sacc[0][r], sacc[1][r]), fmaxf(sacc[2][r], sacc[3][r]));
        }
        for (int off = 8; off >= 1; off >>= 1)
            for (int r = 0; r < 4; r++)
                mx[r] = fmaxf(mx[r], __shfl_xor(mx[r], off));

        float al[4];
        for (int r = 0; r < 4; r++) {
            float mnew = fmaxf(m_i[r], mx[r]);
            al[r] = __expf(m_i[r] - mnew);
            m_i[r] = mnew;
        }
        float rs[4];
        for (int r = 0; r < 4; r++) {
            float s = 0.f;
            for (int nt = 0; nt < 4; nt++) {
                float pv = __expf(sacc[nt][r] - m_i[r]);
                sacc[nt][r] = pv;
                s += pv;
            }
            rs[r] = s;
        }
        for (int off = 8; off >= 1; off >>= 1)
            for (int r = 0; r < 4; r++)
                rs[r] += __shfl_xor(rs[r], off);
        for (int r = 0; r < 4; r++) l_i[r] = l_i[r] * al[r] + rs[r];
        for (int nt = 0; nt < 8; nt++)
            for (int r = 0; r < 4; r++)
                o_acc[nt][r] *= al[r];

        // P -> LDS (swizzled; same-wave rows only, no barrier needed)
        for (int nt = 0; nt < 4; nt++)
            for (int r = 0; r < 4; r++) {
                int row = 16 * wv + quad * 4 + r;
                int cj  = nt * 2 + (ln16 >> 3);
                Ps[row * 64 + ((cj ^ (row & 7)) * 8) + sw8] = f2bf(sacc[nt][r]);
            }

        // ---- O += P V ----
        for (int kc2 = 0; kc2 < 2; kc2++) {
            int lc = kc2 * 4 + quad;
            int prow = 16 * wv + ln16;
            bf16x8 a = *(const bf16x8*)&Ps[prow * 64 + ((lc ^ sw8) * 8)];
            for (int nt = 0; nt < 8; nt++) {
                int h = nt * 16 + ln16;
                bf16x8 b = *(const bf16x8*)&Vs[buf][h * 64 + ((lc ^ sw8) * 8)];
                o_acc[nt] = __builtin_amdgcn_mfma_f32_16x16x32_bf16(a, b, o_acc[nt], 0, 0, 0);
            }
        }

        __syncthreads();   // drains next tile's DMA; releases this buffer
    }

    // epilogue: unnormalized partial O + (m, l)
    const size_t slot = (size_t)bb * NCH + cid;
    for (int nt = 0; nt < 8; nt++)
        for (int r = 0; r < 4; r++)
            Opart[(slot * 64 + 16 * wv + quad * 4 + r) * HD + nt * 16 + ln16] = o_acc[nt][r];
    if (ln16 == 0)
        for (int r = 0; r < 4; r++) {
            Mpart[slot * 64 + 16 * wv + quad * 4 + r] = m_i[r];
            Lpart[slot * 64 + 16 * wv + quad * 4 + r] = l_i[r];
        }
}

// ---------------------------------------------------------------------------
// Kernel 4: merge partial chunks -> final output (fp32).
// ---------------------------------------------------------------------------
__global__ __launch_bounds__(256) void merge_kernel(
        const float* __restrict__ Opart, const float* __restrict__ Mpart,
        const float* __restrict__ Lpart, float* __restrict__ out) {
    const int qt = blockIdx.x;
    const int bb = blockIdx.y;
    const int nch = (qt >> 4) + 1;
    int base = 0;
    for (int q = 63; q > qt; --q) base += (q >> 4) + 1;

    const int tid = threadIdx.x;
    const int q0  = qt * 64;
    for (int e = tid; e < 64 * 32; e += 256) {
        int row = e >> 5;
        int c4  = e & 31;
        float M = -INFINITY;
        float mv[4];
        for (int ch = 0; ch < nch; ch++) {
            mv[ch] = Mpart[((size_t)bb * NCH + base + ch) * 64 + row];
            M = fmaxf(M, mv[ch]);
        }
        float L = 0.f;
        float w[4];
        for (int ch = 0; ch < nch; ch++) {
            w[ch] = __expf(mv[ch] - M);
            L += w[ch] * Lpart[((size_t)bb * NCH + base + ch) * 64 + row];
        }
        float4 acc = {0.f, 0.f, 0.f, 0.f};
        for (int ch = 0; ch < nch; ch++) {
            const float4 o = *(const float4*)(Opart +
                (((size_t)bb * NCH + base + ch) * 64 + row) * HD + c4 * 4);
            acc.x += w[ch] * o.x; acc.y += w[ch] * o.y;
            acc.z += w[ch] * o.z; acc.w += w[ch] * o.w;
        }
        float invL = 1.f / L;
        float4 res = {acc.x * invL, acc.y * invL, acc.z * invL, acc.w * invL};
        *(float4*)(out + ((size_t)bb * TT + q0 + row) * HD + c4 * 4) = res;
    }
}

// ---------------------------------------------------------------------------
extern "C" void kernel_launch(void* const* d_in, const int* in_sizes, int n_in,
                              void* d_out, int out_size, void* d_ws, size_t ws_size,
                              hipStream_t stream) {
    const float* x  = (const float*)d_in[0];
    const float* Wq = (const float*)d_in[1];
    const float* bq = (const float*)d_in[2];
    const float* Wk = (const float*)d_in[3];
    const float* bk = (const float*)d_in[4];
    const float* Wv = (const float*)d_in[5];
    const float* bv = (const float*)d_in[6];
    float* out = (float*)d_out;

    ushort* WT = (ushort*)d_ws;
    ushort* Qb = WT + (size_t)3 * HD * D_MODEL;
    ushort* Kb = Qb + (size_t)M_TOT * HD;
    ushort* Vt = Kb + (size_t)M_TOT * HD;
    float* Opart = (float*)(Vt + (size_t)M_TOT * HD);
    float* Mpart = Opart + (size_t)NB * NCH * 64 * HD;
    float* Lpart = Mpart + (size_t)NB * NCH * 64;

    hipLaunchKernelGGL(wt_kernel, dim3(16, 3), dim3(256), 0, stream, Wq, Wk, Wv, WT);
    hipLaunchKernelGGL(proj_fused, dim3(512), dim3(256), 0, stream,
                       x, WT, bq, bk, bv, Qb, Kb, Vt);
    hipLaunchKernelGGL(attn_part, dim3(NB * NCH), dim3(256), 0, stream,
                       Qb, Kb, Vt, Opart, Mpart, Lpart);
    hipLaunchKernelGGL(merge_kernel, dim3(64, NB), dim3(256), 0, stream,
                       Opart, Mpart, Lpart, out);
}

// Round 6
// 319.624 us; speedup vs baseline: 1.5260x; 1.0394x over previous
//
#include <hip/hip_runtime.h>
#include <math.h>

// Problem constants
#define D_MODEL 2048
#define HD      128
#define NB      4
#define TT      4096
#define M_TOT   (NB * TT)   // 16384
#define NCH     160         // causal s-chunks per batch at BQ=64, 16 tiles/chunk
#define CHT     16          // s-tiles (of 64 keys) per chunk

typedef __attribute__((ext_vector_type(8))) short bf16x8;   // 8 bf16 = 4 VGPRs
typedef __attribute__((ext_vector_type(4))) float f32x4;

__device__ __forceinline__ ushort f2bf(float f) {
    union { float f; unsigned int u; } v; v.f = f;
    unsigned int u = v.u;
    unsigned int r = (u + 0x7FFFu + ((u >> 16) & 1u)) >> 16;   // RNE
    return (ushort)r;
}

// async global->LDS DMA, 16B per lane. LDS dst = wave-uniform base + lane*16.
__device__ __forceinline__ void gload_lds16(const void* g, void* l) {
    __builtin_amdgcn_global_load_lds(
        (const __attribute__((address_space(1))) unsigned int*)g,
        (__attribute__((address_space(3))) unsigned int*)l, 16, 0, 0);
}

// ---------------------------------------------------------------------------
// Kernel 1: WT[p][n][k] = bf16(W_p[k][n]) via LDS tile transpose.
// ---------------------------------------------------------------------------
__global__ __launch_bounds__(256) void wt_kernel(
        const float* __restrict__ Wq, const float* __restrict__ Wk,
        const float* __restrict__ Wv, ushort* __restrict__ WT) {
    const int p  = blockIdx.y;
    const int k0 = blockIdx.x * 128;
    const float* W = (p == 0) ? Wq : ((p == 1) ? Wk : Wv);

    __shared__ ushort Ts[128 * 136];   // [n][kk], stride 272B (16B-aligned rows)

    const int tid = threadIdx.x;
    for (int i = 0; i < 64; i++) {
        int c  = i * 256 + tid;
        int kk = c >> 7, n = c & 127;
        Ts[n * 136 + kk] = f2bf(W[(size_t)(k0 + kk) * 128 + n]);
    }
    __syncthreads();
    for (int i = 0; i < 8; i++) {
        int c = i * 256 + tid;
        int n = c >> 4, j = c & 15;
        *(uint4*)(WT + (size_t)p * (128 * 2048) + (size_t)n * 2048 + k0 + j * 8) =
            *(const uint4*)&Ts[n * 136 + j * 8];
    }
}

// ---------------------------------------------------------------------------
// Kernel 2: fused QKV projection, macro-pipelined.
// Grid 768 = 256 row-tiles x 3 col-thirds; col third == projection matrix p
// (block-uniform). Macro k-step = 128 (x rows read as 512B contiguous), 4
// micro BK=32 MFMA phases. B DMA'd per macro from L2-resident WT into
// XOR-swizzled LDS; A register-prefetched one macro ahead.
// LDS 49.4 KB -> 3 blocks/CU (the extra resident block fills barrier gaps).
// ---------------------------------------------------------------------------
__global__ __launch_bounds__(256, 3) void proj_fused(
        const float* __restrict__ x, const ushort* __restrict__ WT,
        const float* __restrict__ bq, const float* __restrict__ bk, const float* __restrict__ bv,
        ushort* __restrict__ Qb, ushort* __restrict__ Kb, ushort* __restrict__ Vt) {
    const int bx   = blockIdx.x;
    const int row0 = (bx / 3) * 64;
    const int p    = bx % 3;                       // col third == projection index
    const ushort* Wp   = WT + (size_t)p * (128 * 2048);
    const float*  bias = (p == 0) ? bq : ((p == 1) ? bk : bv);

    __shared__ ushort As[64 * 136];    // [m][k0..k0+128), stride 272B (17x16B, conflict-free)
    __shared__ ushort Bs[128 * 128];   // [n][k] unpadded; slot j holds chunk j^(n&15)

    const int tid  = threadIdx.x;
    const int lane = tid & 63;
    const int wv   = tid >> 6;        // 0..3
    const int rw   = wv >> 1;         // row half (32 rows)
    const int cw   = wv & 1;          // col half (64 cols)
    const int quad = lane >> 4;
    const int ln16 = lane & 15;

    // B DMA plan: 2048 chunks of 16B per macro, 8 per thread
    size_t  boff[8];
    ushort* bdst[8];
    for (int i = 0; i < 8; i++) {
        int c = i * 256 + tid;
        int n = c >> 4, j = c & 15;
        int kc = j ^ (n & 15);
        boff[i] = (size_t)n * 2048 + kc * 8;
        bdst[i] = &Bs[(i * 256 + wv * 64) * 8];   // wave-uniform base
    }
    // A plan: 2048 float4 per macro, 8 per thread (rows read as 512B runs)
    int arow[8], apos[8];
    for (int i = 0; i < 8; i++) {
        int c = i * 256 + tid;
        arow[i] = c >> 5;
        apos[i] = c & 31;
    }

    f32x4 acc[2][4];
    for (int m2 = 0; m2 < 2; m2++)
        for (int nt = 0; nt < 4; nt++)
            acc[m2][nt] = (f32x4){0.f, 0.f, 0.f, 0.f};

    float4 areg[8];
    for (int i = 0; i < 8; i++)
        areg[i] = *(const float4*)(x + (size_t)(row0 + arow[i]) * D_MODEL + apos[i] * 4);

    for (int k0 = 0; k0 < D_MODEL; k0 += 128) {
        __syncthreads();   // all waves done reading As/Bs of previous macro
        for (int i = 0; i < 8; i++)
            gload_lds16(Wp + boff[i] + k0, bdst[i]);
        for (int i = 0; i < 8; i++) {
            ushort4 o;
            o.x = f2bf(areg[i].x); o.y = f2bf(areg[i].y);
            o.z = f2bf(areg[i].z); o.w = f2bf(areg[i].w);
            *(ushort4*)&As[arow[i] * 136 + apos[i] * 4] = o;
        }
        __syncthreads();   // drain DMA (vm) + As writes (lgkm)
        if (k0 + 128 < D_MODEL)   // prefetch next macro's A (hidden by micro loop)
            for (int i = 0; i < 8; i++)
                areg[i] = *(const float4*)(x + (size_t)(row0 + arow[i]) * D_MODEL
                                             + k0 + 128 + apos[i] * 4);

        for (int mi = 0; mi < 4; mi++) {
            bf16x8 a[2], b[4];
            for (int m2 = 0; m2 < 2; m2++)
                a[m2] = *(const bf16x8*)&As[(rw * 32 + m2 * 16 + ln16) * 136 + mi * 32 + quad * 8];
            for (int nt = 0; nt < 4; nt++) {
                int n = cw * 64 + nt * 16 + ln16;
                int slot = (mi * 4 + quad) ^ (n & 15);
                b[nt] = *(const bf16x8*)&Bs[n * 128 + slot * 8];
            }
            for (int m2 = 0; m2 < 2; m2++)
                for (int nt = 0; nt < 4; nt++)
                    acc[m2][nt] = __builtin_amdgcn_mfma_f32_16x16x32_bf16(a[m2], b[nt], acc[m2][nt], 0, 0, 0);
        }
    }

    // Epilogue. C/D: col=lane&15, row=quad*4+reg. p is block-uniform.
    for (int nt = 0; nt < 4; nt++) {
        int h  = cw * 64 + nt * 16 + ln16;   // 0..127
        float bc = bias[h];
        for (int m2 = 0; m2 < 2; m2++) {
            int rbase = row0 + rw * 32 + m2 * 16 + quad * 4;
            if (p < 2) {
                ushort* O = (p == 0) ? Qb : Kb;
                for (int r = 0; r < 4; r++)
                    O[(size_t)(rbase + r) * HD + h] = f2bf(acc[m2][nt][r] + bc);
            } else {
                int b = rbase >> 12;
                int t = rbase & 4095;
                ushort4 o;
                o.x = f2bf(acc[m2][nt][0] + bc);
                o.y = f2bf(acc[m2][nt][1] + bc);
                o.z = f2bf(acc[m2][nt][2] + bc);
                o.w = f2bf(acc[m2][nt][3] + bc);
                *(ushort4*)(Vt + ((size_t)b * HD + h) * TT + t) = o;
            }
        }
    }
}

// ---------------------------------------------------------------------------
// Kernel 3: split-s flash attention partials, double-buffered K/V pipeline:
// DMA for tile t+1 issued BEFORE computing tile t; the single barrier per
// tile drains a load that had the whole compute phase to land.
// LDS 72KB -> 2 blocks/CU. 640 blocks, heavy (long-chunk) first.
// ---------------------------------------------------------------------------
#define SCALE 0.08838834764831845f   // 1/sqrt(128)

__global__ __launch_bounds__(256, 2) void attn_part(
        const ushort* __restrict__ Qb, const ushort* __restrict__ Kb,
        const ushort* __restrict__ Vt, float* __restrict__ Opart,
        float* __restrict__ Mpart, float* __restrict__ Lpart) {
    const int blk = blockIdx.x;
    const int bb  = blk & 3;
    const int cid = blk >> 2;          // ascending == qt descending (heavy first)

    int rem = cid, qt = 63;
    for (;;) {
        int cnt = (qt >> 4) + 1;
        if (rem < cnt) break;
        rem -= cnt; --qt;
    }
    const int ch    = rem;
    const int st_lo = ch * CHT;
    const int st_hi = min(qt + 1, st_lo + CHT);
    const int q0    = qt * 64;

    __shared__ ushort Ks[2][64 * 128];   // [s][h]; slot j holds chunk j^(s&15)
    __shared__ ushort Vs[2][128 * 64];   // [h][s]; slot j holds chunk j^(h&7)
    __shared__ ushort Ps[64 * 64];       // [q][s]; slot j holds chunk j^(q&7)

    const int tid  = threadIdx.x;
    const int lane = tid & 63;
    const int wv   = tid >> 6;
    const int quad = lane >> 4;
    const int ln16 = lane & 15;
    const int sw8  = ln16 & 7;

    // DMA plans: K 1024 chunks, V 1024 chunks, 4 each per thread
    int koff[4], voff[4], ldso[4];
    for (int i = 0; i < 4; i++) {
        int c = i * 256 + tid;
        { int r = c >> 4, j = c & 15, kc = j ^ (r & 15);
          koff[i] = r * HD + kc * 8; }
        { int h = c >> 3, j = c & 7, kc = j ^ (h & 7);
          voff[i] = h * TT + kc * 8; }
        ldso[i] = (i * 256 + wv * 64) * 8;    // wave-uniform LDS chunk base
    }
    const ushort* kbase = Kb + (size_t)bb * TT * HD;
    const ushort* vbase = Vt + (size_t)bb * HD * TT;

    // prologue: DMA first tile into buf 0; Q frags into registers meanwhile
    {
        const int s0 = st_lo * 64;
        for (int i = 0; i < 4; i++) gload_lds16(kbase + (size_t)s0 * HD + koff[i], &Ks[0][ldso[i]]);
        for (int i = 0; i < 4; i++) gload_lds16(vbase + s0 + voff[i], &Vs[0][ldso[i]]);
    }
    bf16x8 qf[4];
    {
        const ushort* qrow = Qb + (size_t)(bb * TT + q0 + 16 * wv + ln16) * HD;
        for (int kc = 0; kc < 4; kc++)
            qf[kc] = *(const bf16x8*)(qrow + kc * 32 + quad * 8);
    }

    f32x4 o_acc[8];
    for (int nt = 0; nt < 8; nt++) o_acc[nt] = (f32x4){0.f, 0.f, 0.f, 0.f};
    float m_i[4], l_i[4];
    for (int r = 0; r < 4; r++) { m_i[r] = -INFINITY; l_i[r] = 0.f; }

    __syncthreads();   // first tile's DMA drained

    for (int st = st_lo; st < st_hi; st++) {
        const int s0  = st * 64;
        const int buf = (st - st_lo) & 1;

        // issue next tile's DMA into the other buffer BEFORE computing
        if (st + 1 < st_hi) {
            const int s1 = s0 + 64;
            for (int i = 0; i < 4; i++) gload_lds16(kbase + (size_t)s1 * HD + koff[i], &Ks[buf ^ 1][ldso[i]]);
            for (int i = 0; i < 4; i++) gload_lds16(vbase + s1 + voff[i], &Vs[buf ^ 1][ldso[i]]);
        }

        // ---- S = Q K^T ----
        f32x4 sacc[4];
        for (int nt = 0; nt < 4; nt++) sacc[nt] = (f32x4){0.f, 0.f, 0.f, 0.f};
        for (int kc = 0; kc < 4; kc++) {
            int lc = kc * 4 + quad;
            for (int nt = 0; nt < 4; nt++) {
                int r = nt * 16 + ln16;
                bf16x8 b = *(const bf16x8*)&Ks[buf][r * 128 + ((lc ^ ln16) * 8)];
                sacc[nt] = __builtin_amdgcn_mfma_f32_16x16x32_bf16(qf[kc], b, sacc[nt], 0, 0, 0);
            }
        }

        // ---- scale + causal mask + online softmax (rows wave-private) ----
        const bool diag = (st == qt);
        float mx[4];
        for (int r = 0; r < 4; r++) {
            for (int nt = 0; nt < 4; nt++) {
                float s = sacc[nt][r] * SCALE;
                if (diag) {
                    int sg = s0 + nt * 16 + ln16;
                    int qg = q0 + 16 * wv + quad * 4 + r;
                    if (sg > qg) s = -INFINITY;
                }
                sacc[nt][r] = s;
            }
            mx[r] = fmaxf(fmaxf(sacc[0][r], sacc[1][r]), fmaxf(sacc[2][r], sacc[3][r]));
        }
        for (int off = 8; off >= 1; off >>= 1)
            for (int r = 0; r < 4; r++)
                mx[r] = fmaxf(mx[r], __shfl_xor(mx[r], off));

        float al[4];
        for (int r = 0; r < 4; r++) {
            float mnew = fmaxf(m_i[r], mx[r]);
            al[r] = __expf(m_i[r] - mnew);
            m_i[r] = mnew;
        }
        float rs[4];
        for (int r = 0; r < 4; r++) {
            float s = 0.f;
            for (int nt = 0; nt < 4; nt++) {
                float pv = __expf(sacc[nt][r] - m_i[r]);
                sacc[nt][r] = pv;
                s += pv;
            }
            rs[r] = s;
        }
        for (int off = 8; off >= 1; off >>= 1)
            for (int r = 0; r < 4; r++)
                rs[r] += __shfl_xor(rs[r], off);
        for (int r = 0; r < 4; r++) l_i[r] = l_i[r] * al[r] + rs[r];
        for (int nt = 0; nt < 8; nt++)
            for (int r = 0; r < 4; r++)
                o_acc[nt][r] *= al[r];

        // P -> LDS (swizzled; same-wave rows only, no barrier needed)
        for (int nt = 0; nt < 4; nt++)
            for (int r = 0; r < 4; r++) {
                int row = 16 * wv + quad * 4 + r;
                int cj  = nt * 2 + (ln16 >> 3);
                Ps[row * 64 + ((cj ^ (row & 7)) * 8) + sw8] = f2bf(sacc[nt][r]);
            }

        // ---- O += P V ----
        for (int kc2 = 0; kc2 < 2; kc2++) {
            int lc = kc2 * 4 + quad;
            int prow = 16 * wv + ln16;
            bf16x8 a = *(const bf16x8*)&Ps[prow * 64 + ((lc ^ sw8) * 8)];
            for (int nt = 0; nt < 8; nt++) {
                int h = nt * 16 + ln16;
                bf16x8 b = *(const bf16x8*)&Vs[buf][h * 64 + ((lc ^ sw8) * 8)];
                o_acc[nt] = __builtin_amdgcn_mfma_f32_16x16x32_bf16(a, b, o_acc[nt], 0, 0, 0);
            }
        }

        __syncthreads();   // drains next tile's DMA; releases this buffer
    }

    // epilogue: unnormalized partial O + (m, l)
    const size_t slot = (size_t)bb * NCH + cid;
    for (int nt = 0; nt < 8; nt++)
        for (int r = 0; r < 4; r++)
            Opart[(slot * 64 + 16 * wv + quad * 4 + r) * HD + nt * 16 + ln16] = o_acc[nt][r];
    if (ln16 == 0)
        for (int r = 0; r < 4; r++) {
            Mpart[slot * 64 + 16 * wv + quad * 4 + r] = m_i[r];
            Lpart[slot * 64 + 16 * wv + quad * 4 + r] = l_i[r];
        }
}

// ---------------------------------------------------------------------------
// Kernel 4: merge partial chunks -> final output (fp32).
// ---------------------------------------------------------------------------
__global__ __launch_bounds__(256) void merge_kernel(
        const float* __restrict__ Opart, const float* __restrict__ Mpart,
        const float* __restrict__ Lpart, float* __restrict__ out) {
    const int qt = blockIdx.x;
    const int bb = blockIdx.y;
    const int nch = (qt >> 4) + 1;
    int base = 0;
    for (int q = 63; q > qt; --q) base += (q >> 4) + 1;

    const int tid = threadIdx.x;
    const int q0  = qt * 64;
    for (int e = tid; e < 64 * 32; e += 256) {
        int row = e >> 5;
        int c4  = e & 31;
        float M = -INFINITY;
        float mv[4];
        for (int ch = 0; ch < nch; ch++) {
            mv[ch] = Mpart[((size_t)bb * NCH + base + ch) * 64 + row];
            M = fmaxf(M, mv[ch]);
        }
        float L = 0.f;
        float w[4];
        for (int ch = 0; ch < nch; ch++) {
            w[ch] = __expf(mv[ch] - M);
            L += w[ch] * Lpart[((size_t)bb * NCH + base + ch) * 64 + row];
        }
        float4 acc = {0.f, 0.f, 0.f, 0.f};
        for (int ch = 0; ch < nch; ch++) {
            const float4 o = *(const float4*)(Opart +
                (((size_t)bb * NCH + base + ch) * 64 + row) * HD + c4 * 4);
            acc.x += w[ch] * o.x; acc.y += w[ch] * o.y;
            acc.z += w[ch] * o.z; acc.w += w[ch] * o.w;
        }
        float invL = 1.f / L;
        float4 res = {acc.x * invL, acc.y * invL, acc.z * invL, acc.w * invL};
        *(float4*)(out + ((size_t)bb * TT + q0 + row) * HD + c4 * 4) = res;
    }
}

// ---------------------------------------------------------------------------
extern "C" void kernel_launch(void* const* d_in, const int* in_sizes, int n_in,
                              void* d_out, int out_size, void* d_ws, size_t ws_size,
                              hipStream_t stream) {
    const float* x  = (const float*)d_in[0];
    const float* Wq = (const float*)d_in[1];
    const float* bq = (const float*)d_in[2];
    const float* Wk = (const float*)d_in[3];
    const float* bk = (const float*)d_in[4];
    const float* Wv = (const float*)d_in[5];
    const float* bv = (const float*)d_in[6];
    float* out = (float*)d_out;

    ushort* WT = (ushort*)d_ws;
    ushort* Qb = WT + (size_t)3 * HD * D_MODEL;
    ushort* Kb = Qb + (size_t)M_TOT * HD;
    ushort* Vt = Kb + (size_t)M_TOT * HD;
    float* Opart = (float*)(Vt + (size_t)M_TOT * HD);
    float* Mpart = Opart + (size_t)NB * NCH * 64 * HD;
    float* Lpart = Mpart + (size_t)NB * NCH * 64;

    hipLaunchKernelGGL(wt_kernel, dim3(16, 3), dim3(256), 0, stream, Wq, Wk, Wv, WT);
    hipLaunchKernelGGL(proj_fused, dim3(768), dim3(256), 0, stream,
                       x, WT, bq, bk, bv, Qb, Kb, Vt);
    hipLaunchKernelGGL(attn_part, dim3(NB * NCH), dim3(256), 0, stream,
                       Qb, Kb, Vt, Opart, Mpart, Lpart);
    hipLaunchKernelGGL(merge_kernel, dim3(64, NB), dim3(256), 0, stream,
                       Opart, Mpart, Lpart, out);
}